// Round 2
// baseline (107.640 us; speedup 1.0000x reference)
//
#include <hip/hip_runtime.h>

typedef _Float16 f16x8 __attribute__((ext_vector_type(8)));
typedef float f32x4 __attribute__((ext_vector_type(4)));

static constexpr float kLog2e = 1.44269504088896340736f;

// ws layout (bytes):
//   [0, 65536)        : cfrag — centers as f16 B-fragments, fragment-major
//   [65536, 69632)    : ew[512] float2 = { -beta*log2e*||c_k||^2 , softmax(psi)_k }
#define WS_EW 65536

__device__ __forceinline__ float fast_exp2(float x) {
#if __has_builtin(__builtin_amdgcn_exp2f)
  return __builtin_amdgcn_exp2f(x);
#else
  return exp2f(x);
#endif
}

// ---------------------------------------------------------------------------
// Prep (fused): one block, 512 threads (thread == center index).
//  - softmax(psi) -> w
//  - e2 = -beta*log2e*||c||^2 ; store interleaved ew[k] = {e2, w}
//  - centers fp32 -> f16 B-fragments (fragment-major scatter)
//  - threads 0..63 zero d_out (harness poisons it to 0xAA)
// Fragment layout (verified R1, absmax 5.5e-17): B-lane = quad*16 + (n&15),
// tile t = n>>4, k = kk*32 + quad*8 + j  ->  idx = (t*2+kk)*64 + lane.
// ---------------------------------------------------------------------------
__global__ __launch_bounds__(512) void prep_kernel(
    const float* __restrict__ centers, const float* __restrict__ psi,
    const float* __restrict__ beta, _Float16* __restrict__ cfrag,
    float2* __restrict__ ew, float* __restrict__ out) {
  __shared__ float red[8];
  const int n = threadIdx.x;   // center index 0..511
  const int lane = n & 63;
  const int wid = n >> 6;
  const float b = beta[0];
  const float kco = -b * kLog2e;

  // ||c||^2 in fp32 (exact) + stash the row for the f16 conversion
  float4 row[16];
  const float4* crow = (const float4*)(centers + n * 64);
  float c2 = 0.f;
#pragma unroll
  for (int i = 0; i < 16; ++i) {
    row[i] = crow[i];
    c2 = fmaf(row[i].x, row[i].x, c2); c2 = fmaf(row[i].y, row[i].y, c2);
    c2 = fmaf(row[i].z, row[i].z, c2); c2 = fmaf(row[i].w, row[i].w, c2);
  }

  // softmax over 512 psi
  const float p = psi[n];
  float m = p;
#pragma unroll
  for (int d = 1; d < 64; d <<= 1) m = fmaxf(m, __shfl_xor(m, d, 64));
  if (lane == 0) red[wid] = m;
  __syncthreads();
  float mx = red[0];
#pragma unroll
  for (int i = 1; i < 8; ++i) mx = fmaxf(mx, red[i]);
  __syncthreads();
  const float ex = fast_exp2((p - mx) * kLog2e);
  float ssum = ex;
#pragma unroll
  for (int d = 1; d < 64; d <<= 1) ssum += __shfl_xor(ssum, d, 64);
  if (lane == 0) red[wid] = ssum;
  __syncthreads();
  float tot = 0.f;
#pragma unroll
  for (int i = 0; i < 8; ++i) tot += red[i];

  ew[n] = make_float2(kco * c2, ex / tot);

  // scatter this center's 64 elems into B-fragment slots (8x 16B stores)
  const int t = n >> 4;
  const int l15 = n & 15;
#pragma unroll
  for (int kk = 0; kk < 2; ++kk) {
#pragma unroll
    for (int quad = 0; quad < 4; ++quad) {
      const int idx = (t * 2 + kk) * 64 + quad * 16 + l15;
      const float4 v0 = row[kk * 8 + quad * 2];
      const float4 v1 = row[kk * 8 + quad * 2 + 1];
      f16x8 h;
      h[0] = (_Float16)v0.x; h[1] = (_Float16)v0.y;
      h[2] = (_Float16)v0.z; h[3] = (_Float16)v0.w;
      h[4] = (_Float16)v1.x; h[5] = (_Float16)v1.y;
      h[6] = (_Float16)v1.z; h[7] = (_Float16)v1.w;
      *(f16x8*)(cfrag + (size_t)idx * 8) = h;
    }
  }

  if (n < 64) out[n] = 0.f;
}

// ---------------------------------------------------------------------------
// Main kernel: 1024 blocks x 256 threads (4 waves). Block owns 128 rows (one
// batch slice; 16 blocks per batch). Wave owns 32 rows (2 row-tiles of 16),
// iterates 32 center-tiles of 16. cC=2*beta*log2e is folded into the A
// fragments, and (kco*||f||^2 + e2) rides the MFMA C operand, so the
// epilogue is just min + exp2 + add per element.
// ---------------------------------------------------------------------------
__global__ __launch_bounds__(256, 4) void score_kernel(
    const float* __restrict__ F, const _Float16* __restrict__ cfrag,
    const float2* __restrict__ ew, const float* __restrict__ beta,
    float* __restrict__ out) {
  __shared__ float f2s[128];
  __shared__ float wsum[4];
  const int tid = threadIdx.x;
  const int lane = tid & 63;
  const int wv = tid >> 6;    // wave 0..3
  const int quad = lane >> 4; // 0..3
  const int l15 = lane & 15;
  const int R0 = blockIdx.x * 128;

  const float b = beta[0];
  const float cC = 2.f * b * kLog2e;   // folded into A fragments
  const float kco = -b * kLog2e;

  // A fragments (scaled by cC, fp32->f16 in-reg) + exact fp32 ||f||^2.
  // A layout: m = lane&15, k = kk*32 + quad*8 + j.
  f16x8 a[2][2];
#pragma unroll
  for (int rt = 0; rt < 2; ++rt) {
    const int row = R0 + wv * 32 + rt * 16 + l15;
    const float* fr = F + row * 64 + quad * 8;
    float ssq = 0.f;
#pragma unroll
    for (int kk = 0; kk < 2; ++kk) {
      const float4 v0 = *(const float4*)(fr + kk * 32);
      const float4 v1 = *(const float4*)(fr + kk * 32 + 4);
      ssq = fmaf(v0.x, v0.x, ssq); ssq = fmaf(v0.y, v0.y, ssq);
      ssq = fmaf(v0.z, v0.z, ssq); ssq = fmaf(v0.w, v0.w, ssq);
      ssq = fmaf(v1.x, v1.x, ssq); ssq = fmaf(v1.y, v1.y, ssq);
      ssq = fmaf(v1.z, v1.z, ssq); ssq = fmaf(v1.w, v1.w, ssq);
      a[rt][kk][0] = (_Float16)(cC * v0.x); a[rt][kk][1] = (_Float16)(cC * v0.y);
      a[rt][kk][2] = (_Float16)(cC * v0.z); a[rt][kk][3] = (_Float16)(cC * v0.w);
      a[rt][kk][4] = (_Float16)(cC * v1.x); a[rt][kk][5] = (_Float16)(cC * v1.y);
      a[rt][kk][6] = (_Float16)(cC * v1.z); a[rt][kk][7] = (_Float16)(cC * v1.w);
    }
    // lane holds 16 of row (lane&15)'s 64 elems; fold across the 4 quads
    ssq += __shfl_xor(ssq, 16, 64);
    ssq += __shfl_xor(ssq, 32, 64);
    if (quad == 0) f2s[wv * 32 + rt * 16 + l15] = ssq;
  }
  __syncthreads();

  // kco*||f||^2 in C/D layout: row_in_tile = quad*4 + r
  float p0[2][4];
#pragma unroll
  for (int rt = 0; rt < 2; ++rt)
#pragma unroll
    for (int r = 0; r < 4; ++r)
      p0[rt][r] = kco * f2s[wv * 32 + rt * 16 + quad * 4 + r];

  float s = 0.f;
#pragma unroll 2
  for (int t = 0; t < 32; ++t) {
    const f16x8 b0 = *(const f16x8*)(cfrag + (size_t)((t * 2 + 0) * 64 + lane) * 8);
    const f16x8 b1 = *(const f16x8*)(cfrag + (size_t)((t * 2 + 1) * 64 + lane) * 8);
    const float2 ewv = ew[t * 16 + l15];  // col = t*16 + (lane&15)
    // C init = kco*f2 + e2 ; D = C + cC*(f.c) = full exp2 argument
    f32x4 acc0 = {p0[0][0] + ewv.x, p0[0][1] + ewv.x, p0[0][2] + ewv.x, p0[0][3] + ewv.x};
    f32x4 acc1 = {p0[1][0] + ewv.x, p0[1][1] + ewv.x, p0[1][2] + ewv.x, p0[1][3] + ewv.x};
    acc0 = __builtin_amdgcn_mfma_f32_16x16x32_f16(a[0][0], b0, acc0, 0, 0, 0);
    acc0 = __builtin_amdgcn_mfma_f32_16x16x32_f16(a[0][1], b1, acc0, 0, 0, 0);
    acc1 = __builtin_amdgcn_mfma_f32_16x16x32_f16(a[1][0], b0, acc1, 0, 0, 0);
    acc1 = __builtin_amdgcn_mfma_f32_16x16x32_f16(a[1][1], b1, acc1, 0, 0, 0);
    float esum = 0.f;
#pragma unroll
    for (int r = 0; r < 4; ++r) {
      esum += fast_exp2(fminf(acc0[r], 0.f));   // clamp == max(dist2,0)
      esum += fast_exp2(fminf(acc1[r], 0.f));
    }
    s = fmaf(ewv.y, esum, s);  // w depends only on col == lane&15
  }

  // block-wide sum: lanes hold disjoint (row,col) partials
#pragma unroll
  for (int d = 1; d < 64; d <<= 1) s += __shfl_xor(s, d, 64);
  if (lane == 0) wsum[wv] = s;
  __syncthreads();
  if (tid == 0) {
    const float tot = wsum[0] + wsum[1] + wsum[2] + wsum[3];
    atomicAdd(out + (blockIdx.x >> 4), tot * (1.0f / 2048.0f));
  }
}

extern "C" void kernel_launch(void* const* d_in, const int* in_sizes, int n_in,
                              void* d_out, int out_size, void* d_ws, size_t ws_size,
                              hipStream_t stream) {
  const float* F = (const float*)d_in[0];        // (64, 2048, 64) fp32
  const float* centers = (const float*)d_in[1];  // (512, 64) fp32
  const float* psi = (const float*)d_in[2];      // (512,) fp32
  const float* beta = (const float*)d_in[3];     // scalar fp32
  float* out = (float*)d_out;                    // (64,) fp32
  char* ws = (char*)d_ws;
  _Float16* cfrag = (_Float16*)ws;
  float2* ew = (float2*)(ws + WS_EW);

  prep_kernel<<<1, 512, 0, stream>>>(centers, psi, beta, cfrag, ew, out);
  score_kernel<<<1024, 256, 0, stream>>>(F, cfrag, ew, beta, out);
}

// Round 3
// 101.904 us; speedup vs baseline: 1.0563x; 1.0563x over previous
//
#include <hip/hip_runtime.h>

typedef _Float16 f16x8 __attribute__((ext_vector_type(8)));
typedef float f32x4 __attribute__((ext_vector_type(4)));

static constexpr float kLog2e = 1.44269504088896340736f;

// ws layout (bytes):
//   [0, 65536)        : cfrag — centers as f16 B-fragments, fragment-major
//   [65536, 69632)    : ew[512] float2 = { -beta*log2e*||c_k||^2 , softmax(psi)_k }
#define WS_EW 65536

__device__ __forceinline__ float fast_exp2(float x) {
#if __has_builtin(__builtin_amdgcn_exp2f)
  return __builtin_amdgcn_exp2f(x);
#else
  return exp2f(x);
#endif
}

// ---------------------------------------------------------------------------
// Prep (fused, verified R2: absmax 1.7e-18): one block, 512 threads.
//  - softmax(psi) -> w ; e2 = -beta*log2e*||c||^2 ; ew[k] = {e2, w}
//  - centers fp32 -> f16 B-fragments (fragment-major scatter)
//  - threads 0..63 zero d_out (harness poisons it to 0xAA)
// Fragment layout: B-lane = quad*16 + (n&15), tile t = n>>4,
// k = kk*32 + quad*8 + j  ->  idx = (t*2+kk)*64 + lane.
// ---------------------------------------------------------------------------
__global__ __launch_bounds__(512) void prep_kernel(
    const float* __restrict__ centers, const float* __restrict__ psi,
    const float* __restrict__ beta, _Float16* __restrict__ cfrag,
    float2* __restrict__ ew, float* __restrict__ out) {
  __shared__ float red[8];
  const int n = threadIdx.x;   // center index 0..511
  const int lane = n & 63;
  const int wid = n >> 6;
  const float b = beta[0];
  const float kco = -b * kLog2e;

  float4 row[16];
  const float4* crow = (const float4*)(centers + n * 64);
  float c2 = 0.f;
#pragma unroll
  for (int i = 0; i < 16; ++i) {
    row[i] = crow[i];
    c2 = fmaf(row[i].x, row[i].x, c2); c2 = fmaf(row[i].y, row[i].y, c2);
    c2 = fmaf(row[i].z, row[i].z, c2); c2 = fmaf(row[i].w, row[i].w, c2);
  }

  const float p = psi[n];
  float m = p;
#pragma unroll
  for (int d = 1; d < 64; d <<= 1) m = fmaxf(m, __shfl_xor(m, d, 64));
  if (lane == 0) red[wid] = m;
  __syncthreads();
  float mx = red[0];
#pragma unroll
  for (int i = 1; i < 8; ++i) mx = fmaxf(mx, red[i]);
  __syncthreads();
  const float ex = fast_exp2((p - mx) * kLog2e);
  float ssum = ex;
#pragma unroll
  for (int d = 1; d < 64; d <<= 1) ssum += __shfl_xor(ssum, d, 64);
  if (lane == 0) red[wid] = ssum;
  __syncthreads();
  float tot = 0.f;
#pragma unroll
  for (int i = 0; i < 8; ++i) tot += red[i];

  ew[n] = make_float2(kco * c2, ex / tot);

  const int t = n >> 4;
  const int l15 = n & 15;
#pragma unroll
  for (int kk = 0; kk < 2; ++kk) {
#pragma unroll
    for (int quad = 0; quad < 4; ++quad) {
      const int idx = (t * 2 + kk) * 64 + quad * 16 + l15;
      const float4 v0 = row[kk * 8 + quad * 2];
      const float4 v1 = row[kk * 8 + quad * 2 + 1];
      f16x8 h;
      h[0] = (_Float16)v0.x; h[1] = (_Float16)v0.y;
      h[2] = (_Float16)v0.z; h[3] = (_Float16)v0.w;
      h[4] = (_Float16)v1.x; h[5] = (_Float16)v1.y;
      h[6] = (_Float16)v1.z; h[7] = (_Float16)v1.w;
      *(f16x8*)(cfrag + (size_t)idx * 8) = h;
    }
  }

  if (n < 64) out[n] = 0.f;
}

// ---------------------------------------------------------------------------
// Main kernel: 512 blocks x 256 threads (4 waves), 2 blocks/CU. Block owns
// 256 rows (8 blocks per batch). Wave owns 64 rows (4 row-tiles of 16) —
// doubles B-fragment reuse per load vs R2, halving L2-side cfrag traffic
// (268 MB -> 134 MB). Per tile-iter: 2 B loads, 8 MFMAs, 16-elem exp2
// epilogue. cC=2*beta*log2e folded into A; (kco*||f||^2+e2) rides MFMA C.
// ---------------------------------------------------------------------------
__global__ __launch_bounds__(256, 2) void score_kernel(
    const float* __restrict__ F, const _Float16* __restrict__ cfrag,
    const float2* __restrict__ ew, const float* __restrict__ beta,
    float* __restrict__ out) {
  __shared__ float f2s[256];
  __shared__ float wsum[4];
  const int tid = threadIdx.x;
  const int lane = tid & 63;
  const int wv = tid >> 6;    // wave 0..3
  const int quad = lane >> 4; // 0..3
  const int l15 = lane & 15;
  const int R0 = blockIdx.x * 256;

  const float b = beta[0];
  const float cC = 2.f * b * kLog2e;   // folded into A fragments
  const float kco = -b * kLog2e;

  // A fragments (scaled by cC, fp32->f16 in-reg) + exact fp32 ||f||^2.
  // A layout: m = lane&15, k = kk*32 + quad*8 + j.
  f16x8 a[4][2];
#pragma unroll
  for (int rt = 0; rt < 4; ++rt) {
    const int row = R0 + wv * 64 + rt * 16 + l15;
    const float* fr = F + row * 64 + quad * 8;
    float ssq = 0.f;
#pragma unroll
    for (int kk = 0; kk < 2; ++kk) {
      const float4 v0 = *(const float4*)(fr + kk * 32);
      const float4 v1 = *(const float4*)(fr + kk * 32 + 4);
      ssq = fmaf(v0.x, v0.x, ssq); ssq = fmaf(v0.y, v0.y, ssq);
      ssq = fmaf(v0.z, v0.z, ssq); ssq = fmaf(v0.w, v0.w, ssq);
      ssq = fmaf(v1.x, v1.x, ssq); ssq = fmaf(v1.y, v1.y, ssq);
      ssq = fmaf(v1.z, v1.z, ssq); ssq = fmaf(v1.w, v1.w, ssq);
      a[rt][kk][0] = (_Float16)(cC * v0.x); a[rt][kk][1] = (_Float16)(cC * v0.y);
      a[rt][kk][2] = (_Float16)(cC * v0.z); a[rt][kk][3] = (_Float16)(cC * v0.w);
      a[rt][kk][4] = (_Float16)(cC * v1.x); a[rt][kk][5] = (_Float16)(cC * v1.y);
      a[rt][kk][6] = (_Float16)(cC * v1.z); a[rt][kk][7] = (_Float16)(cC * v1.w);
    }
    ssq += __shfl_xor(ssq, 16, 64);
    ssq += __shfl_xor(ssq, 32, 64);
    if (quad == 0) f2s[wv * 64 + rt * 16 + l15] = ssq;
  }
  __syncthreads();

  // kco*||f||^2 in C/D layout: row_in_tile = quad*4 + r
  float p0[4][4];
#pragma unroll
  for (int rt = 0; rt < 4; ++rt)
#pragma unroll
    for (int r = 0; r < 4; ++r)
      p0[rt][r] = kco * f2s[wv * 64 + rt * 16 + quad * 4 + r];

  float s = 0.f;
#pragma unroll 2
  for (int t = 0; t < 32; ++t) {
    const f16x8 b0 = *(const f16x8*)(cfrag + (size_t)((t * 2 + 0) * 64 + lane) * 8);
    const f16x8 b1 = *(const f16x8*)(cfrag + (size_t)((t * 2 + 1) * 64 + lane) * 8);
    const float2 ewv = ew[t * 16 + l15];  // col = t*16 + (lane&15)
    float esum = 0.f;
#pragma unroll
    for (int rt = 0; rt < 4; ++rt) {
      // C init = kco*f2 + e2 ; D = C + cC*(f.c) = full exp2 argument
      f32x4 acc = {p0[rt][0] + ewv.x, p0[rt][1] + ewv.x,
                   p0[rt][2] + ewv.x, p0[rt][3] + ewv.x};
      acc = __builtin_amdgcn_mfma_f32_16x16x32_f16(a[rt][0], b0, acc, 0, 0, 0);
      acc = __builtin_amdgcn_mfma_f32_16x16x32_f16(a[rt][1], b1, acc, 0, 0, 0);
#pragma unroll
      for (int r = 0; r < 4; ++r)
        esum += fast_exp2(fminf(acc[r], 0.f));   // clamp == max(dist2,0)
    }
    s = fmaf(ewv.y, esum, s);  // w depends only on col == lane&15
  }

  // block-wide sum: lanes hold disjoint (row,col) partials
#pragma unroll
  for (int d = 1; d < 64; d <<= 1) s += __shfl_xor(s, d, 64);
  if (lane == 0) wsum[wv] = s;
  __syncthreads();
  if (tid == 0) {
    const float tot = wsum[0] + wsum[1] + wsum[2] + wsum[3];
    atomicAdd(out + (blockIdx.x >> 3), tot * (1.0f / 2048.0f));
  }
}

extern "C" void kernel_launch(void* const* d_in, const int* in_sizes, int n_in,
                              void* d_out, int out_size, void* d_ws, size_t ws_size,
                              hipStream_t stream) {
  const float* F = (const float*)d_in[0];        // (64, 2048, 64) fp32
  const float* centers = (const float*)d_in[1];  // (512, 64) fp32
  const float* psi = (const float*)d_in[2];      // (512,) fp32
  const float* beta = (const float*)d_in[3];     // scalar fp32
  float* out = (float*)d_out;                    // (64,) fp32
  char* ws = (char*)d_ws;
  _Float16* cfrag = (_Float16*)ws;
  float2* ew = (float2*)(ws + WS_EW);

  prep_kernel<<<1, 512, 0, stream>>>(centers, psi, beta, cfrag, ew, out);
  score_kernel<<<512, 256, 0, stream>>>(F, cfrag, ew, beta, out);
}